// Round 2
// baseline (259.226 us; speedup 1.0000x reference)
//
#include <hip/hip_runtime.h>

// LIF spiking layer forward: x (B,C,T) fp32 -> spikes (B,C,T) fp32.
// Recurrence per row r=(b,c):
//   rst   = spk_{t-1} * Vth[c]
//   mem_t = (mem_{t-1} - rst)*beta + x_t*alpha
//   spk_t = (mem_t - Vth[c] > 0) ? 1 : 0
// Bit-exact vs numpy: no FMA contraction; rst handled via select since
// 1.0*Vth == Vth exactly and mem - 0.0 == mem exactly.

constexpr int T_LEN = 2000;
constexpr int NV    = 10;            // float4 per chunk
constexpr int CH    = NV * 4;        // 40 timesteps per chunk
constexpr int NC    = T_LEN / CH;    // 50 chunks (even)

__device__ __forceinline__ void load_chunk(float4 (&buf)[NV], const float4* __restrict__ xr, int c) {
#pragma unroll
    for (int v = 0; v < NV; ++v) buf[v] = xr[c * NV + v];
}

__device__ __forceinline__ float lif_step(float xval, float alpha, float beta, float vth,
                                          float& mem, float& vdiff, bool& spk) {
#pragma clang fp contract(off)
    float xa = xval * alpha;                 // x_t * alpha (separate mul, like np)
    // Speculative both-branch update; bit-exact vs (mem - rst)*beta + xa:
    //   spk==1: rst = 1.0*Vth = Vth, mem-Vth == vdiff (computed last step)
    //   spk==0: rst = 0.0*Vth = 0.0, mem-0.0 == mem
    float p0 = mem   * beta;
    float p1 = vdiff * beta;
    float q0 = p0 + xa;
    float q1 = p1 + xa;
    mem   = spk ? q1 : q0;
    vdiff = mem - vth;
    spk   = vdiff > 0.0f;
    return spk ? 1.0f : 0.0f;
}

__device__ __forceinline__ void compute_chunk(const float4 (&buf)[NV], float4* __restrict__ orow, int c,
                                              float alpha, float beta, float vth,
                                              float& mem, float& vdiff, bool& spk) {
#pragma clang fp contract(off)
#pragma unroll
    for (int v = 0; v < NV; ++v) {
        float4 xv = buf[v];
        float4 s;
        s.x = lif_step(xv.x, alpha, beta, vth, mem, vdiff, spk);
        s.y = lif_step(xv.y, alpha, beta, vth, mem, vdiff, spk);
        s.z = lif_step(xv.z, alpha, beta, vth, mem, vdiff, spk);
        s.w = lif_step(xv.w, alpha, beta, vth, mem, vdiff, spk);
        orow[c * NV + v] = s;
    }
}

__global__ __launch_bounds__(64) void lif_fwd_kernel(const float* __restrict__ x,
                                                     const float* __restrict__ alpha_p,
                                                     const float* __restrict__ beta_p,
                                                     const float* __restrict__ vth_p,
                                                     float* __restrict__ out,
                                                     int C, int rows) {
#pragma clang fp contract(off)
    const int row = blockIdx.x * 64 + threadIdx.x;
    if (row >= rows) return;

    const float alpha = alpha_p[0];
    const float beta  = beta_p[0];
    const float vth   = vth_p[(unsigned)row % (unsigned)C];

    const float4* __restrict__ xr   = reinterpret_cast<const float4*>(x + (size_t)row * T_LEN);
    float4* __restrict__       orow = reinterpret_cast<float4*>(out + (size_t)row * T_LEN);

    float mem = 0.0f, vdiff = 0.0f;
    bool  spk = false;
    // vdiff init: only consumed when spk==true, so value irrelevant at t=0.

    float4 A[NV], B[NV];
    load_chunk(A, xr, 0);

    // Double-buffered pipeline: loads for chunk c+1 in flight while computing chunk c.
    for (int i = 0; i < NC / 2; ++i) {
        const int c = 2 * i;
        load_chunk(B, xr, c + 1);
        compute_chunk(A, orow, c, alpha, beta, vth, mem, vdiff, spk);
        if (c + 2 < NC) load_chunk(A, xr, c + 2);
        compute_chunk(B, orow, c + 1, alpha, beta, vth, mem, vdiff, spk);
    }
}

extern "C" void kernel_launch(void* const* d_in, const int* in_sizes, int n_in,
                              void* d_out, int out_size, void* d_ws, size_t ws_size,
                              hipStream_t stream) {
    const float* x     = (const float*)d_in[0];
    const float* alpha = (const float*)d_in[1];
    const float* beta  = (const float*)d_in[2];
    const float* vth   = (const float*)d_in[3];
    float* out = (float*)d_out;

    const int C    = in_sizes[3];            // 256
    const int rows = in_sizes[0] / T_LEN;    // B*C = 16384

    dim3 grid((rows + 63) / 64), block(64);
    lif_fwd_kernel<<<grid, block, 0, stream>>>(x, alpha, beta, vth, out, C, rows);
}